// Round 4
// baseline (4545.313 us; speedup 1.0000x reference)
//
#include <hip/hip_runtime.h>
#include <hip/hip_fp16.h>
#include <math.h>

typedef _Float16 f16;
typedef __attribute__((ext_vector_type(8))) _Float16 f16x8;
typedef __attribute__((ext_vector_type(4))) float f32x4;
typedef unsigned int u32;

#define B_ 128
#define S_ 256
#define I_ 128
#define H_ 1024
#define G_ 4096
#define T_ 128
#define F_ 64

// ---------------- workspace layout (bytes) ----------------
#define BAR_OFF   0ull
#define HB0_OFF   4096ull
#define HB1_OFF   (HB0_OFF + 262144ull)
#define X16_OFF   (HB1_OFF + 262144ull)          // [S][B][I] f16
#define BPE_OFF   (X16_OFF + 8388608ull)         // enc B-frag pack: [64][36][4][64][8] f16
#define BPD_OFF   (BPE_OFF + 9437184ull)         // dec W_eff pack:  [64][32][4][64][8] f16
#define DWT_OFF   (BPD_OFF + 8388608ull)         // (dense_W - out_W)^T : [1024][64] f32
#define BEN_OFF   (DWT_OFF + 262144ull)          // enc bias [4096] f32
#define BDE_OFF   (BEN_OFF + 16384ull)           // dec bias (t>=2) [4096] f32
#define BBA_OFF   (BDE_OFF + 16384ull)           // dec base bias (b_ih+b_hh) [4096] f32
#define OWP_OFF   (BBA_OFF + 16384ull)           // out_W pack [32][4][64][8] f16
#define HIST_OFF  (OWP_OFF + 131072ull)          // dec h history [128][128][1024] f16
#define C_OFF     (HIST_OFF + 33554432ull)       // c state [128][1024] f32
#define B1_OFF    (C_OFF + 524288ull)            // decoder t=1 bias [128][4096] f32
// total ~63.4 MB

// =================== prep kernel 1 ===================
__global__ void k_prep(const float* __restrict__ x,
                       const float* __restrict__ eWih, const float* __restrict__ eWhh,
                       const float* __restrict__ eb_ih, const float* __restrict__ eb_hh,
                       const float* __restrict__ dW,   const float* __restrict__ db,
                       const float* __restrict__ dWih, const float* __restrict__ db_ih,
                       const float* __restrict__ db_hh,
                       const float* __restrict__ oW,   const float* __restrict__ ob,
                       char* ws)
{
  f16*  h0  = (f16*)(ws + HB0_OFF);
  f16*  x16 = (f16*)(ws + X16_OFF);
  f16*  bpe = (f16*)(ws + BPE_OFF);
  float* dwt = (float*)(ws + DWT_OFF);
  float* ben = (float*)(ws + BEN_OFF);
  float* bde = (float*)(ws + BDE_OFF);
  float* bba = (float*)(ws + BBA_OFF);
  f16*  owp = (f16*)(ws + OWP_OFF);
  float* cbuf = (float*)(ws + C_OFF);

  int tid = blockIdx.x*blockDim.x + threadIdx.x;
  int np  = gridDim.x*blockDim.x;

  for (int i = tid; i < B_*H_; i += np) { h0[i] = (f16)0.f; cbuf[i] = 0.f; }

  for (int i = tid; i < S_*B_*I_; i += np) {
    int ii = i & 127; int b = (i >> 7) & 127; int s = i >> 14;
    x16[i] = (f16)x[((size_t)b*S_ + s)*I_ + ii];
  }

  for (int g = tid; g < G_; g += np) {
    ben[g] = eb_ih[g] + eb_hh[g];
    float base = db_ih[g] + db_hh[g];
    bba[g] = base;
    float acc = base;
    for (int f = 0; f < F_; ++f) acc += ob[f] * dWih[(size_t)g*F_ + f];
    bde[g] = acc;
  }

  for (int i = tid; i < H_*F_; i += np) {
    int f = i & 63; int k = i >> 6;
    dwt[i] = dW[(size_t)f*H_ + k] - oW[(size_t)f*H_ + k];
  }

  // encoder B-frag pack: k-order = [x(128) | h(1024)]
  for (int i = tid; i < 64*36*4*64*8; i += np) {
    int j = i & 7; int lane = (i >> 3) & 63; int nt = (i >> 9) & 3;
    int rest = i >> 11; int q = rest % 36; int wgN = rest / 36;
    int colg = nt*H_ + wgN*16 + (lane & 15);
    int k = q*32 + ((lane >> 4) << 3) + j;
    float v = (k < 128) ? eWih[(size_t)colg*I_ + k] : eWhh[(size_t)colg*H_ + (k - 128)];
    bpe[i] = (f16)v;
  }

  // out_W pack for final GEMM
  for (int i = tid; i < 32*4*64*8; i += np) {
    int j = i & 7; int lane = (i >> 3) & 63; int nt = (i >> 9) & 3; int q = i >> 11;
    int f = nt*16 + (lane & 15);
    int k = q*32 + ((lane >> 4) << 3) + j;
    owp[i] = (f16)oW[(size_t)f*H_ + k];
  }
}

// =================== prep kernel 2: W_eff = dec_W_hh + dec_W_ih @ out_W ===================
__global__ void k_packdec(const float* __restrict__ dWih, const float* __restrict__ dWhh,
                          const float* __restrict__ oW, char* ws)
{
  f16* bpd = (f16*)(ws + BPD_OFF);
  __shared__ float sW[4][64];
  int cg0 = blockIdx.x * 4;
  for (int i = threadIdx.x; i < 256; i += 256)
    sW[i >> 6][i & 63] = dWih[(size_t)(cg0 + (i >> 6))*64 + (i & 63)];
  __syncthreads();
  for (int u = 0; u < 4; ++u) {
    int colg = cg0 + u;
    for (int k = threadIdx.x; k < 1024; k += 256) {
      float acc = dWhh[(size_t)colg*1024 + k];
      #pragma unroll
      for (int f = 0; f < 64; ++f) acc += sW[u][f] * oW[(size_t)f*1024 + k];
      int nt = colg >> 10, w16 = colg & 1023;
      int wgN = w16 >> 4, cl = w16 & 15;
      int q = k >> 5, hi = (k >> 3) & 3, j = k & 7;
      bpd[((((size_t)wgN*32 + q)*4 + nt)*64 + hi*16 + cl)*8 + j] = (f16)acc;
    }
  }
}

// =================== per-timestep LSTM kernel ===================
// grid 256, block 256 (4 waves). WG(wgM,wgN): batch rows [wgM*32,+32),
// hidden units [wgN*16,+16) -> 64 gate cols (i,f,g,o x 16).
// Wave w: mrow=(w>>1)*16 rows, nh=w&1 -> 32 of 64 gate cols.
// NQ=36: encoder (k = [x(4q) | h(32q)]). NQ=32: decoder (k = h only).
// Stream-ordered launches replace the grid barrier: no coop launch, no fences.
template<int NQ>
__global__ __launch_bounds__(256, 1) void k_step(
    const f16* __restrict__ x_t,      // x16 + t*B*I (NQ==36 only)
    const f16* __restrict__ bpack,    // bpe (NQ=36) or bpd (NQ=32)
    const f16* __restrict__ hsrc, f16* __restrict__ hdst,
    float* __restrict__ cbuf,
    const float* __restrict__ bias, int biasRowStride,  // 0=broadcast[4096], 4096=per-row
    f16* __restrict__ histDst)        // hist + (t-1)*B*H, or nullptr
{
  __shared__ float gsm[32][64];
  const int tid = threadIdx.x;
  const int w = tid >> 6, l = tid & 63;
  const int wg = blockIdx.x;
  const int wgM = wg >> 6, wgN = wg & 63;
  const int nh = w & 1, mrow = (w >> 1) * 16;
  const int arow = wgM*32 + mrow + (l & 15);
  const int koff = (l >> 4) << 3;

  // B fragments for this WG's 64 gate cols (reloaded each step; L2/IF-hot)
  f16x8 bw[NQ][2];
  #pragma unroll
  for (int q = 0; q < NQ; ++q) {
    #pragma unroll
    for (int n = 0; n < 2; ++n) {
      bw[q][n] = *(const f16x8*)(bpack + ((((size_t)wgN*NQ + q)*4 + (nh*2 + n))*64 + l)*8);
    }
  }

  f32x4 acc0 = {0.f,0.f,0.f,0.f}, acc1 = {0.f,0.f,0.f,0.f};
  const f16* hr = hsrc + (size_t)arow*H_ + koff;
  if (NQ == 36) {
    const f16* xr = x_t + (size_t)arow*I_ + koff;
    #pragma unroll
    for (int q = 0; q < 4; ++q) {
      f16x8 a = *(const f16x8*)(xr + q*32);
      acc0 = __builtin_amdgcn_mfma_f32_16x16x32_f16(a, bw[q][0], acc0, 0,0,0);
      acc1 = __builtin_amdgcn_mfma_f32_16x16x32_f16(a, bw[q][1], acc1, 0,0,0);
    }
    #pragma unroll
    for (int q = 0; q < 32; ++q) {
      f16x8 a = *(const f16x8*)(hr + q*32);
      acc0 = __builtin_amdgcn_mfma_f32_16x16x32_f16(a, bw[4+q][0], acc0, 0,0,0);
      acc1 = __builtin_amdgcn_mfma_f32_16x16x32_f16(a, bw[4+q][1], acc1, 0,0,0);
    }
  } else {
    #pragma unroll
    for (int q = 0; q < 32; ++q) {
      f16x8 a = *(const f16x8*)(hr + q*32);
      acc0 = __builtin_amdgcn_mfma_f32_16x16x32_f16(a, bw[q][0], acc0, 0,0,0);
      acc1 = __builtin_amdgcn_mfma_f32_16x16x32_f16(a, bw[q][1], acc1, 0,0,0);
    }
  }

  // C/D layout (m89-verified): col = lane&15, row = (lane>>4)*4 + reg
  #pragma unroll
  for (int reg = 0; reg < 4; ++reg) {
    int cr = mrow + ((l >> 4) << 2) + reg;
    gsm[cr][nh*32 + (l & 15)]      = acc0[reg];
    gsm[cr][nh*32 + 16 + (l & 15)] = acc1[reg];
  }
  __syncthreads();

  // pointwise: 512 (row, unit) cells, 2 per thread; c in global f32
  #pragma unroll
  for (int rep = 0; rep < 2; ++rep) {
    int idx = tid + rep*256; int r = idx >> 4; int jj = idx & 15;
    int bg = wgM*32 + r; int cbase = wgN*16 + jj;
    const float* bb = bias + (size_t)bg*biasRowStride;
    float gi = gsm[r][jj]      + bb[0*H_ + cbase];
    float gf = gsm[r][16 + jj] + bb[1*H_ + cbase];
    float gg = gsm[r][32 + jj] + bb[2*H_ + cbase];
    float go = gsm[r][48 + jj] + bb[3*H_ + cbase];
    float si = 1.f/(1.f + __expf(-gi));
    float sf = 1.f/(1.f + __expf(-gf));
    float sg = tanhf(gg);
    float so = 1.f/(1.f + __expf(-go));
    size_t ci = (size_t)bg*H_ + cbase;
    float cn = sf*cbuf[ci] + si*sg;
    cbuf[ci] = cn;
    float hn = so * tanhf(cn);
    hdst[ci] = (f16)hn;
    if (histDst) histDst[ci] = (f16)hn;
  }
}

// =================== decoder t=1 bias: b1 = (h_n(dW-oW)^T + db) dWih^T + bba ===================
__global__ void k_bias1(const f16* __restrict__ hn, const float* __restrict__ dwt,
                        const float* __restrict__ db, const float* __restrict__ dWih,
                        const float* __restrict__ bba, float* __restrict__ b1)
{
  __shared__ float zs[64];
  int b = blockIdx.x;            // 128 blocks, one batch row each
  int tid = threadIdx.x;         // 256
  if (tid < 64) {
    float acc = db[tid];
    const f16* hp = hn + (size_t)b*H_;
    for (int k = 0; k < H_; ++k) acc += (float)hp[k] * dwt[k*F_ + tid];
    zs[tid] = acc;
  }
  __syncthreads();
  for (int u = 0; u < 16; ++u) {
    int colg = tid + u*256;
    float a = bba[colg];
    #pragma unroll
    for (int f = 0; f < F_; ++f) a += zs[f] * dWih[(size_t)colg*F_ + f];
    b1[(size_t)b*G_ + colg] = a;
  }
}

// =================== final out projection: out = hist @ out_W^T + out_b ===================
__global__ __launch_bounds__(256) void k_out(const char* __restrict__ ws,
                                             const float* __restrict__ ob,
                                             float* __restrict__ out)
{
  const f16* hist = (const f16*)(ws + HIST_OFF);
  const f16* owp  = (const f16*)(ws + OWP_OFF);
  int tid = threadIdx.x; int w = tid >> 6, l = tid & 63;
  int r0 = blockIdx.x*64 + w*16;
  f32x4 acc[4] = {{0.f,0.f,0.f,0.f},{0.f,0.f,0.f,0.f},{0.f,0.f,0.f,0.f},{0.f,0.f,0.f,0.f}};
  for (int q = 0; q < 32; ++q) {
    int row = r0 + (l & 15);
    f16x8 a = *(const f16x8*)(hist + (size_t)row*H_ + q*32 + ((l >> 4) << 3));
    #pragma unroll
    for (int nt = 0; nt < 4; ++nt) {
      f16x8 b = *(const f16x8*)(owp + (((size_t)(q*4 + nt))*64 + l)*8);
      acc[nt] = __builtin_amdgcn_mfma_f32_16x16x32_f16(a, b, acc[nt], 0, 0, 0);
    }
  }
  #pragma unroll
  for (int nt = 0; nt < 4; ++nt) {
    #pragma unroll
    for (int reg = 0; reg < 4; ++reg) {
      int rr = r0 + ((l >> 4) << 2) + reg;
      int bb = rr & 127; int tt = rr >> 7;   // hist row = (t-1)*B + b
      int f = nt*16 + (l & 15);
      out[((size_t)bb*T_ + tt)*F_ + f] = acc[nt][reg] + ob[f];
    }
  }
}

// =================== host launcher ===================
extern "C" void kernel_launch(void* const* d_in, const int* in_sizes, int n_in,
                              void* d_out, int out_size, void* d_ws, size_t ws_size,
                              hipStream_t stream)
{
  const float* x     = (const float*)d_in[0];
  const float* eWih  = (const float*)d_in[1];
  const float* eWhh  = (const float*)d_in[2];
  const float* eb_ih = (const float*)d_in[3];
  const float* eb_hh = (const float*)d_in[4];
  const float* dW    = (const float*)d_in[5];
  const float* dbv   = (const float*)d_in[6];
  const float* dWih  = (const float*)d_in[7];
  const float* dWhh  = (const float*)d_in[8];
  const float* db_ih = (const float*)d_in[9];
  const float* db_hh = (const float*)d_in[10];
  const float* oW    = (const float*)d_in[11];
  const float* ob    = (const float*)d_in[12];
  char* ws = (char*)d_ws;

  hipLaunchKernelGGL(k_prep, dim3(2048), dim3(256), 0, stream,
                     x, eWih, eWhh, eb_ih, eb_hh, dW, dbv, dWih, db_ih, db_hh, oW, ob, ws);
  hipLaunchKernelGGL(k_packdec, dim3(1024), dim3(256), 0, stream, dWih, dWhh, oW, ws);

  const f16* x16p = (const f16*)(ws + X16_OFF);
  const f16* bpep = (const f16*)(ws + BPE_OFF);
  const f16* bpdp = (const f16*)(ws + BPD_OFF);
  const float* dwtp = (const float*)(ws + DWT_OFF);
  const float* benp = (const float*)(ws + BEN_OFF);
  const float* bdep = (const float*)(ws + BDE_OFF);
  const float* bbap = (const float*)(ws + BBA_OFF);
  float* b1p  = (float*)(ws + B1_OFF);
  float* cbufp = (float*)(ws + C_OFF);
  f16* hb[2] = { (f16*)(ws + HB0_OFF), (f16*)(ws + HB1_OFF) };
  f16* histp = (f16*)(ws + HIST_OFF);

  // ---- encoder: 256 stream-ordered steps ----
  for (int t = 0; t < S_; ++t) {
    hipLaunchKernelGGL(HIP_KERNEL_NAME(k_step<36>), dim3(256), dim3(256), 0, stream,
                       x16p + (size_t)t*B_*I_, bpep,
                       hb[t & 1], hb[(t & 1) ^ 1], cbufp,
                       benp, 0, (f16*)nullptr);
  }

  // ---- decoder t=1 bias correction ----
  hipLaunchKernelGGL(k_bias1, dim3(128), dim3(256), 0, stream,
                     hb[0], dwtp, dbv, dWih, bbap, b1p);

  // ---- decoder: 128 stream-ordered steps ----
  for (int t = 1; t <= T_; ++t) {
    const float* bias = (t == 1) ? (const float*)b1p : bdep;
    int rs = (t == 1) ? G_ : 0;
    hipLaunchKernelGGL(HIP_KERNEL_NAME(k_step<32>), dim3(256), dim3(256), 0, stream,
                       (const f16*)nullptr, bpdp,
                       hb[(t - 1) & 1], hb[t & 1], cbufp,
                       bias, rs, histp + (size_t)(t - 1)*B_*H_);
  }

  hipLaunchKernelGGL(k_out, dim3(256), dim3(256), 0, stream,
                     (const char*)ws, ob, (float*)d_out);
}